// Round 1
// baseline (10870.540 us; speedup 1.0000x reference)
//
#include <hip/hip_runtime.h>
#include <hip/hip_bf16.h>
#include <stdint.h>

#define BB 256
#define TT 512
#define HH 512

typedef __bf16 bf16x8 __attribute__((ext_vector_type(8)));
typedef float f32x4 __attribute__((ext_vector_type(4)));

__device__ __forceinline__ bf16x8 ldfrag(const unsigned short* p) {
    uint4 u = *reinterpret_cast<const uint4*>(p);
    return __builtin_bit_cast(bf16x8, u);
}

__device__ __forceinline__ float sigm(float x) { return 1.0f / (1.0f + __expf(-x)); }
__device__ __forceinline__ float tanh_fast(float x) { return 2.0f / (1.0f + __expf(-2.0f * x)) - 1.0f; }

// round-to-nearest-even f32 -> bf16 (values here are finite/small; no NaN path needed)
__device__ __forceinline__ unsigned short f2bf(float f) {
    unsigned int u = __builtin_bit_cast(unsigned int, f);
    unsigned int r = (u + 0x7fffu + ((u >> 16) & 1u)) >> 16;
    return (unsigned short)r;
}

// ---- prep: cast the three big weight matrices to bf16 ----
__global__ __launch_bounds__(256) void prep_cast(const float* __restrict__ a,
                                                 const float* __restrict__ b,
                                                 const float* __restrict__ c,
                                                 unsigned short* __restrict__ oa,
                                                 unsigned short* __restrict__ ob,
                                                 unsigned short* __restrict__ oc) {
    const int n = 2048 * 512;
    for (int i = blockIdx.x * blockDim.x + threadIdx.x; i < n; i += gridDim.x * blockDim.x) {
        oa[i] = f2bf(a[i]);
        ob[i] = f2bf(b[i]);
        oc[i] = f2bf(c[i]);
    }
}

// ---- prep: zero the parity-1 h buffers (read at t=0) and both c states ----
__global__ __launch_bounds__(256) void prep_zero(unsigned short* __restrict__ h0p,
                                                 unsigned short* __restrict__ h2p,
                                                 float* __restrict__ c0,
                                                 float* __restrict__ c1) {
    const int n = BB * HH;
    for (int i = blockIdx.x * blockDim.x + threadIdx.x; i < n; i += gridDim.x * blockDim.x) {
        h0p[i] = 0; h2p[i] = 0; c0[i] = 0.f; c1[i] = 0.f;
    }
}

// ---- one pipelined super-step: blocks 0..127 do layer0 @ t=s, blocks 128..255 do layer1 @ t=s-1 ----
// Per wave: 16 batch rows x 16 h-cols x 4 gate blocks, K = 512 per matmul, mfma 16x16x32 bf16.
// A-frag: lane holds A[m0 + (lane&15)][kb*32 + (lane>>4)*8 + j], j=0..7 (contiguous k -> 16B load)
// B-frag: lane holds W[gate_row = g*512 + n0 + (lane&15)][same k]         (contiguous k -> 16B load)
// C/D   : col = lane&15, row = (lane>>4)*4 + reg   [measured m89]
__global__ __launch_bounds__(256) void lstm_step(
    const float* __restrict__ x,        // [B][T]
    const float* __restrict__ wih0,     // [2048]
    const unsigned short* __restrict__ Whh0,
    const unsigned short* __restrict__ Wih1,
    const unsigned short* __restrict__ Whh1,
    unsigned short* __restrict__ h0buf, // 2 x [B][H] bf16, parity by t
    unsigned short* __restrict__ h2buf, // 2 x [B][H] bf16, parity by t
    float* __restrict__ c0s,            // [B][H] f32
    float* __restrict__ c1s,            // [B][H] f32
    int s)
{
    const int wave = threadIdx.x >> 6;
    const int lane = threadIdx.x & 63;
    const bool l1 = blockIdx.x >= 128;
    const int t = l1 ? s - 1 : s;
    if (t < 0 || t >= TT) return;

    const int p  = ((blockIdx.x & 127) << 2) | wave;  // 0..511
    const int m0 = (p >> 5) << 4;                     // batch-row tile base
    const int n0 = (p & 31) << 4;                     // h-col tile base
    const int nn = lane & 15;
    const int kq = lane >> 4;
    const int fragoff = kq * 8;

    f32x4 acc[4];
    #pragma unroll
    for (int g = 0; g < 4; ++g) acc[g] = (f32x4){0.f, 0.f, 0.f, 0.f};

    auto runk = [&](const unsigned short* A, const unsigned short* W) {
        const unsigned short* pa = A + (m0 + nn) * HH + fragoff;
        const unsigned short* pw = W + (n0 + nn) * HH + fragoff;
        #pragma unroll 4
        for (int kb = 0; kb < 16; ++kb) {
            bf16x8 a = ldfrag(pa + kb * 32);
            #pragma unroll
            for (int g = 0; g < 4; ++g) {
                bf16x8 b = ldfrag(pw + g * (512 * HH) + kb * 32);
                acc[g] = __builtin_amdgcn_mfma_f32_16x16x32_bf16(a, b, acc[g], 0, 0, 0);
            }
        }
    };

    unsigned short* hout;
    float* cst;
    if (!l1) {
        runk(h0buf + ((t - 1) & 1) * (BB * HH), Whh0);   // h0_{t-1} @ Whh0^T
        hout = h0buf + (t & 1) * (BB * HH);
        cst  = c0s;
    } else {
        runk(h0buf + (t & 1) * (BB * HH), Wih1);         // h1_t     @ Wih1^T
        runk(h2buf + ((t - 1) & 1) * (BB * HH), Whh1);   // h2_{t-1} @ Whh1^T
        hout = h2buf + (t & 1) * (BB * HH);
        cst  = c1s;
    }

    const int col = n0 + nn;
    float wi0 = 0.f, wf0 = 0.f, wg0 = 0.f, wo0 = 0.f;
    if (!l1) {
        wi0 = wih0[col];
        wf0 = wih0[512 + col];
        wg0 = wih0[1024 + col];
        wo0 = wih0[1536 + col];
    }

    #pragma unroll
    for (int r = 0; r < 4; ++r) {
        const int m = m0 + kq * 4 + r;
        float gi = acc[0][r], gf = acc[1][r], gg = acc[2][r], go = acc[3][r];
        if (!l1) {
            const float xv = x[m * TT + t];
            gi += xv * wi0; gf += xv * wf0; gg += xv * wg0; go += xv * wo0;
        }
        const float cold = cst[m * HH + col];
        const float cn = sigm(gf) * cold + sigm(gi) * tanh_fast(gg);
        cst[m * HH + col] = cn;
        const float h = sigm(go) * tanh_fast(cn);
        hout[m * HH + col] = f2bf(h);
    }
}

// ---- final: LayerNorm(last h2) @ w_out^T, one 64-lane block per batch row ----
__global__ __launch_bounds__(64) void ln_out_k(const unsigned short* __restrict__ h2,
                                               const float* __restrict__ gamma,
                                               const float* __restrict__ beta,
                                               const float* __restrict__ wout,
                                               float* __restrict__ out)
{
    const int row = blockIdx.x;
    const int lane = threadIdx.x;
    const unsigned short* hr = h2 + row * HH + lane * 8;
    uint4 u = *reinterpret_cast<const uint4*>(hr);
    unsigned short us[8];
    *reinterpret_cast<uint4*>(us) = u;
    float v[8];
    #pragma unroll
    for (int j = 0; j < 8; ++j) {
        unsigned int w = ((unsigned int)us[j]) << 16;
        v[j] = __builtin_bit_cast(float, w);
    }
    float sum = 0.f;
    #pragma unroll
    for (int j = 0; j < 8; ++j) sum += v[j];
    #pragma unroll
    for (int o = 32; o >= 1; o >>= 1) sum += __shfl_xor(sum, o);
    const float mu = sum * (1.0f / 512.0f);

    float vs = 0.f;
    #pragma unroll
    for (int j = 0; j < 8; ++j) { float d = v[j] - mu; vs += d * d; }
    #pragma unroll
    for (int o = 32; o >= 1; o >>= 1) vs += __shfl_xor(vs, o);
    const float inv = rsqrtf(vs * (1.0f / 512.0f) + 1e-5f);

    float dot = 0.f;
    #pragma unroll
    for (int j = 0; j < 8; ++j) {
        const int c = lane * 8 + j;
        dot += ((v[j] - mu) * inv * gamma[c] + beta[c]) * wout[c];
    }
    #pragma unroll
    for (int o = 32; o >= 1; o >>= 1) dot += __shfl_xor(dot, o);
    if (lane == 0) out[row] = dot;
}

extern "C" void kernel_launch(void* const* d_in, const int* in_sizes, int n_in,
                              void* d_out, int out_size, void* d_ws, size_t ws_size,
                              hipStream_t stream) {
    const float* x     = (const float*)d_in[0];
    const float* wih0  = (const float*)d_in[1];
    const float* whh0  = (const float*)d_in[2];
    const float* wih1  = (const float*)d_in[3];
    const float* whh1  = (const float*)d_in[4];
    const float* gamma = (const float*)d_in[5];
    const float* beta  = (const float*)d_in[6];
    const float* wout  = (const float*)d_in[7];

    // ws layout (8 MB total):
    //   [0,2M)   Whh0 bf16   [2M,4M) Wih1 bf16   [4M,6M) Whh1 bf16
    //   [6M,6.5M) h0buf dbuf bf16   [6.5M,7M) h2buf dbuf bf16
    //   [7M,7.5M) c0 f32           [7.5M,8M) c1 f32
    char* ws = (char*)d_ws;
    unsigned short* Whh0b = (unsigned short*)(ws);
    unsigned short* Wih1b = (unsigned short*)(ws + (2u << 20));
    unsigned short* Whh1b = (unsigned short*)(ws + (4u << 20));
    unsigned short* h0buf = (unsigned short*)(ws + (6u << 20));
    unsigned short* h2buf = (unsigned short*)(ws + (6u << 20) + (512u << 10));
    float* c0s = (float*)(ws + (7u << 20));
    float* c1s = (float*)(ws + (7u << 20) + (512u << 10));

    hipLaunchKernelGGL(prep_cast, dim3(1024), dim3(256), 0, stream,
                       whh0, wih1, whh1, Whh0b, Wih1b, Whh1b);
    hipLaunchKernelGGL(prep_zero, dim3(128), dim3(256), 0, stream,
                       h0buf + BB * HH, h2buf + BB * HH, c0s, c1s);

    for (int s = 0; s <= TT; ++s) {
        hipLaunchKernelGGL(lstm_step, dim3(256), dim3(256), 0, stream,
                           x, wih0, Whh0b, Wih1b, Whh1b, h0buf, h2buf, c0s, c1s, s);
    }

    // final h2 is parity (T-1)&1 == 1
    hipLaunchKernelGGL(ln_out_k, dim3(BB), dim3(64), 0, stream,
                       h2buf + BB * HH, gamma, beta, wout, (float*)d_out);
}

// Round 2
// 9170.485 us; speedup vs baseline: 1.1854x; 1.1854x over previous
//
#include <hip/hip_runtime.h>
#include <stdint.h>

#define BB 256
#define TT 512
#define HH 512
#define NBLK 192
#define SSTR 16
#define BBHH (BB*HH)

typedef __bf16 bf16x8 __attribute__((ext_vector_type(8)));
typedef float f32x4 __attribute__((ext_vector_type(4)));

static __device__ __forceinline__ unsigned short f2bf(float f) {
    unsigned int u = __builtin_bit_cast(unsigned int, f);
    unsigned int r = (u + 0x7fffu + ((u >> 16) & 1u)) >> 16;
    return (unsigned short)r;
}
static __device__ __forceinline__ bf16x8 ldfrag(const unsigned short* p) {
    uint4 u = *reinterpret_cast<const uint4*>(p);
    return __builtin_bit_cast(bf16x8, u);
}
static __device__ __forceinline__ bf16x8 packbf8(const float* p) {
    float4 a = *reinterpret_cast<const float4*>(p);
    float4 b = *reinterpret_cast<const float4*>(p + 4);
    unsigned short us[8] = { f2bf(a.x), f2bf(a.y), f2bf(a.z), f2bf(a.w),
                             f2bf(b.x), f2bf(b.y), f2bf(b.z), f2bf(b.w) };
    uint4 u; __builtin_memcpy(&u, us, 16);
    return __builtin_bit_cast(bf16x8, u);
}
static __device__ __forceinline__ float sigm(float x){ return 1.0f/(1.0f+__expf(-x)); }
static __device__ __forceinline__ float tanh_fast(float x){ return 2.0f/(1.0f+__expf(-2.0f*x)) - 1.0f; }

// zero the parity-1 h buffers (read as h_{-1}) and the barrier slots
__global__ __launch_bounds__(256) void prep_zero(unsigned short* __restrict__ h1p,
                                                 unsigned short* __restrict__ h2p,
                                                 int* __restrict__ slots) {
    int i = blockIdx.x * blockDim.x + threadIdx.x;
    for (int k = i; k < BBHH; k += gridDim.x * blockDim.x) { h1p[k] = 0; h2p[k] = 0; }
    if (i < NBLK * SSTR) slots[i] = 0;
}

// Persistent pipelined 2-layer LSTM.
// Blocks 0..63   : layer-0, block tile 64 rows x 32 hcols (rg=b>>4, ct=b&15).
//                  wave w: rows m0=rg*64+(w>>1)*32 (32), hcols n0=ct*32+(w&1)*16 (16).
// Blocks 64..191 : layer-1, block tile 64 rows x 16 hcols (rg=bl>>5, ctl=bl&31).
//                  wave w: pair=w>>1 selects row half (32 rows), mm=w&1 selects matmul
//                  (0: Wih1 @ h1_t, 1: Whh1 @ h2_{t-1}; mm==1 combines partials + cell update).
// Every wave: 16 hcols x 4 gates x K=512 weight slice in 256 VGPRs (loaded once, f32->bf16),
// 128 MFMA 16x16x32 per step. c-state lives in 8 f32 registers per lane, never in memory.
// Super-step s: L0 computes t=s (s<512), L1 computes t=s-1 (s>=1); grid barrier between steps.
__global__ __launch_bounds__(256, 1) void lstm_persist(
    const float* __restrict__ x,        // [B][T]
    const float* __restrict__ wih0,     // [2048]
    const float* __restrict__ Whh0,     // [2048][512] f32
    const float* __restrict__ Wih1,     // [2048][512] f32
    const float* __restrict__ Whh1,     // [2048][512] f32
    unsigned short* __restrict__ h1buf, // 2 x [B][H] bf16 (parity by t)
    unsigned short* __restrict__ h2buf, // 2 x [B][H] bf16 (parity by t)
    int* __restrict__ slots)
{
    __shared__ float xch[2][32][65];    // [pair][acc elem][lane], +1 pad vs bank conflicts

    const int tid = threadIdx.x;
    const int w   = tid >> 6;
    const int l   = tid & 63;
    const int ln  = l & 15;
    const int kq  = l >> 4;
    const int bid = blockIdx.x;
    const bool isL0 = bid < 64;

    int m0, n0, mm = 0, pair = 0;
    const float* Wsrc;
    if (isL0) {
        const int rg = bid >> 4, ct = bid & 15;
        m0 = rg * 64 + (w >> 1) * 32;
        n0 = ct * 32 + (w & 1) * 16;
        Wsrc = Whh0;
    } else {
        const int bl = bid - 64;
        const int rg = bl >> 5, ctl = bl & 31;
        pair = w >> 1;
        mm   = w & 1;
        m0 = rg * 64 + pair * 32;
        n0 = ctl * 16;
        Wsrc = mm ? Whh1 : Wih1;
    }

    // ---- one-time weight preload into registers (B-fragments, 256 VGPR) ----
    bf16x8 wb[16][4];
    #pragma unroll
    for (int g = 0; g < 4; ++g) {
        const float* wr = Wsrc + (g * HH + n0 + ln) * HH + kq * 8;
        #pragma unroll
        for (int kb = 0; kb < 16; ++kb)
            wb[kb][g] = packbf8(wr + kb * 32);
    }

    float wi0 = 0.f, wf0 = 0.f, wg0 = 0.f, wo0 = 0.f;
    if (isL0) {
        wi0 = wih0[n0 + ln];
        wf0 = wih0[512 + n0 + ln];
        wg0 = wih0[1024 + n0 + ln];
        wo0 = wih0[1536 + n0 + ln];
    }

    float cst[8];
    #pragma unroll
    for (int i = 0; i < 8; ++i) cst[i] = 0.f;

    for (int s = 0; s <= TT; ++s) {
        const bool active = isL0 ? (s < TT) : (s >= 1);
        if (active) {
            const int t = isL0 ? s : s - 1;
            const unsigned short* hp;
            if (isL0)      hp = h1buf + ((t - 1) & 1) * BBHH;  // h1_{t-1}
            else if (mm)   hp = h2buf + ((t - 1) & 1) * BBHH;  // h2_{t-1}
            else           hp = h1buf + (t & 1) * BBHH;        // h1_t

            f32x4 acc[2][4];
            #pragma unroll
            for (int rt = 0; rt < 2; ++rt)
                #pragma unroll
                for (int g = 0; g < 4; ++g) acc[rt][g] = (f32x4){0.f,0.f,0.f,0.f};

            const unsigned short* pa0 = hp + (m0 + ln) * HH + kq * 8;
            #pragma unroll
            for (int kb = 0; kb < 16; ++kb) {
                bf16x8 a0 = ldfrag(pa0 + kb * 32);
                bf16x8 a1 = ldfrag(pa0 + 16 * HH + kb * 32);
                #pragma unroll
                for (int g = 0; g < 4; ++g) {
                    acc[0][g] = __builtin_amdgcn_mfma_f32_16x16x32_bf16(a0, wb[kb][g], acc[0][g], 0, 0, 0);
                    acc[1][g] = __builtin_amdgcn_mfma_f32_16x16x32_bf16(a1, wb[kb][g], acc[1][g], 0, 0, 0);
                }
            }

            if (isL0) {
                unsigned short* ho = h1buf + (t & 1) * BBHH;
                #pragma unroll
                for (int rt = 0; rt < 2; ++rt)
                #pragma unroll
                for (int r = 0; r < 4; ++r) {
                    const int m = m0 + rt * 16 + kq * 4 + r;
                    const float xv = x[m * TT + t];
                    const float gi = acc[rt][0][r] + xv * wi0;
                    const float gf = acc[rt][1][r] + xv * wf0;
                    const float gg = acc[rt][2][r] + xv * wg0;
                    const float go = acc[rt][3][r] + xv * wo0;
                    const float c  = sigm(gf) * cst[rt*4+r] + sigm(gi) * tanh_fast(gg);
                    cst[rt*4+r] = c;
                    ho[m * HH + n0 + ln] = f2bf(sigm(go) * tanh_fast(c));
                }
            } else if (mm == 0) {
                #pragma unroll
                for (int rt = 0; rt < 2; ++rt)
                #pragma unroll
                for (int g = 0; g < 4; ++g)
                #pragma unroll
                for (int r = 0; r < 4; ++r)
                    xch[pair][rt*16 + g*4 + r][l] = acc[rt][g][r];
            }

            if (!isL0) {
                __syncthreads();  // publish mm==0 partials (block-uniform branch)
                if (mm == 1) {
                    unsigned short* ho = h2buf + (t & 1) * BBHH;
                    #pragma unroll
                    for (int rt = 0; rt < 2; ++rt)
                    #pragma unroll
                    for (int r = 0; r < 4; ++r) {
                        const int i0 = rt * 16 + r;
                        const float gi = acc[rt][0][r] + xch[pair][i0 + 0][l];
                        const float gf = acc[rt][1][r] + xch[pair][i0 + 4][l];
                        const float gg = acc[rt][2][r] + xch[pair][i0 + 8][l];
                        const float go = acc[rt][3][r] + xch[pair][i0 + 12][l];
                        const int m = m0 + rt * 16 + kq * 4 + r;
                        const float c = sigm(gf) * cst[rt*4+r] + sigm(gi) * tanh_fast(gg);
                        cst[rt*4+r] = c;
                        ho[m * HH + n0 + ln] = f2bf(sigm(go) * tanh_fast(c));
                    }
                }
            }
        }

        // ---- grid barrier (skip after final step) ----
        if (s < TT) {
            __syncthreads();
            if (tid == 0) {
                __builtin_amdgcn_fence(__ATOMIC_RELEASE, "agent");
                __hip_atomic_store(slots + bid * SSTR, s + 1,
                                   __ATOMIC_RELAXED, __HIP_MEMORY_SCOPE_AGENT);
            }
            if (tid < NBLK) {
                while (__hip_atomic_load(slots + tid * SSTR,
                                         __ATOMIC_RELAXED, __HIP_MEMORY_SCOPE_AGENT) < s + 1) {
                    __builtin_amdgcn_s_sleep(1);
                }
            }
            __builtin_amdgcn_fence(__ATOMIC_ACQUIRE, "agent");
            __syncthreads();
        }
    }
}

// ---- final: LayerNorm(last h2) @ w_out^T, one 64-lane block per batch row ----
__global__ __launch_bounds__(64) void ln_out_k(const unsigned short* __restrict__ h2,
                                               const float* __restrict__ gamma,
                                               const float* __restrict__ beta,
                                               const float* __restrict__ wout,
                                               float* __restrict__ out)
{
    const int row = blockIdx.x;
    const int lane = threadIdx.x;
    uint4 u = *reinterpret_cast<const uint4*>(h2 + row * HH + lane * 8);
    unsigned short us[8];
    *reinterpret_cast<uint4*>(us) = u;
    float v[8];
    #pragma unroll
    for (int j = 0; j < 8; ++j) {
        unsigned int w = ((unsigned int)us[j]) << 16;
        v[j] = __builtin_bit_cast(float, w);
    }
    float sum = 0.f;
    #pragma unroll
    for (int j = 0; j < 8; ++j) sum += v[j];
    #pragma unroll
    for (int o = 32; o >= 1; o >>= 1) sum += __shfl_xor(sum, o);
    const float mu = sum * (1.0f / 512.0f);

    float vs = 0.f;
    #pragma unroll
    for (int j = 0; j < 8; ++j) { float d = v[j] - mu; vs += d * d; }
    #pragma unroll
    for (int o = 32; o >= 1; o >>= 1) vs += __shfl_xor(vs, o);
    const float inv = rsqrtf(vs * (1.0f / 512.0f) + 1e-5f);

    float dot = 0.f;
    #pragma unroll
    for (int j = 0; j < 8; ++j) {
        const int c = lane * 8 + j;
        dot += ((v[j] - mu) * inv * gamma[c] + beta[c]) * wout[c];
    }
    #pragma unroll
    for (int o = 32; o >= 1; o >>= 1) dot += __shfl_xor(dot, o);
    if (lane == 0) out[row] = dot;
}

extern "C" void kernel_launch(void* const* d_in, const int* in_sizes, int n_in,
                              void* d_out, int out_size, void* d_ws, size_t ws_size,
                              hipStream_t stream) {
    const float* x     = (const float*)d_in[0];
    const float* wih0  = (const float*)d_in[1];
    const float* whh0  = (const float*)d_in[2];
    const float* wih1  = (const float*)d_in[3];
    const float* whh1  = (const float*)d_in[4];
    const float* gamma = (const float*)d_in[5];
    const float* beta  = (const float*)d_in[6];
    const float* wout  = (const float*)d_in[7];

    // ws layout: h1buf 2x256KB | h2buf 2x256KB | slots 12KB
    char* ws = (char*)d_ws;
    unsigned short* h1buf = (unsigned short*)(ws);
    unsigned short* h2buf = (unsigned short*)(ws + (512u << 10));
    int* slots            = (int*)(ws + (1024u << 10));

    hipLaunchKernelGGL(prep_zero, dim3(64), dim3(256), 0, stream,
                       h1buf + BBHH, h2buf + BBHH, slots);

    hipLaunchKernelGGL(lstm_persist, dim3(NBLK), dim3(256), 0, stream,
                       x, wih0, whh0, wih1, whh1, h1buf, h2buf, slots);

    // final h2 is parity (T-1)&1 == 1
    hipLaunchKernelGGL(ln_out_k, dim3(BB), dim3(64), 0, stream,
                       h2buf + BBHH, gamma, beta, wout, (float*)d_out);
}